// Round 2
// baseline (860.799 us; speedup 1.0000x reference)
//
#include <hip/hip_runtime.h>
#include <hip/hip_fp16.h>

#define INVS 0.35355339059327373f  // 1/(2*sqrt(2))
#define CCH 28
#define VSTR 32                    // padded voxel stride in halves (64 B = 1 cache sector)

typedef float f32x4 __attribute__((ext_vector_type(4)));

// 8-coeff 3D Haar butterfly. c[b], b = u*4+v*2+w; o[p*4+q*2+r].
__device__ __forceinline__ void haar8(const float c[8], float o[8]) {
    float t00p = c[0] + c[1], t00m = c[0] - c[1];
    float t01p = c[2] + c[3], t01m = c[2] - c[3];
    float t10p = c[4] + c[5], t10m = c[4] - c[5];
    float t11p = c[6] + c[7], t11m = c[6] - c[7];
    float u00p = t00p + t01p, u00m = t00m + t01m;
    float u01p = t00p - t01p, u01m = t00m - t01m;
    float u10p = t10p + t11p, u10m = t10m + t11m;
    float u11p = t10p - t11p, u11m = t10m - t11m;
    o[0] = (u00p + u10p) * INVS;  o[1] = (u00m + u10m) * INVS;
    o[2] = (u01p + u11p) * INVS;  o[3] = (u01m + u11m) * INVS;
    o[4] = (u00p - u10p) * INVS;  o[5] = (u00m - u10m) * INVS;
    o[6] = (u01p - u11p) * INVS;  o[7] = (u01m - u11m) * INVS;
}

// Levels 0/1: channel-first fp16 output (C, 2D, 2D, 2D). x-fastest threads.
template <int LOGD, typename TA>
__global__ void idwt_cf_h(const TA* __restrict__ approx,
                          const float* __restrict__ details,
                          __half* __restrict__ out) {
    constexpr int D  = 1 << LOGD;
    constexpr int D3 = D * D * D;
    int t  = blockIdx.x * blockDim.x + threadIdx.x;
    int xc = t & (D - 1);
    int yc = (t >> LOGD) & (D - 1);
    int zc = (t >> (2 * LOGD)) & (D - 1);
    int c  = t >> (3 * LOGD);
    if (c >= CCH) return;
    int base = c * D3 + ((zc * D + yc) * D + xc);
    float cf[8];
    cf[0] = (float)approx[base];
#pragma unroll
    for (int j = 0; j < 7; ++j) cf[j + 1] = details[j * (CCH * D3) + base];
    float o[8];
    haar8(cf, o);
    constexpr int D2 = 2 * D;
    __half2* outv = (__half2*)out;  // half2 = x-pair
    int ob = (((c * D2 + 2 * zc) * D2 + 2 * yc) * D + xc);
    __half2 h01, h23, h45, h67;
    h01.x = __float2half(o[0]); h01.y = __float2half(o[1]);
    h23.x = __float2half(o[2]); h23.y = __float2half(o[3]);
    h45.x = __float2half(o[4]); h45.y = __float2half(o[5]);
    h67.x = __float2half(o[6]); h67.y = __float2half(o[7]);
    outv[ob]              = h01;
    outv[ob + D]          = h23;
    outv[ob + D2 * D]     = h45;
    outv[ob + D2 * D + D] = h67;
}

// Level 2: (28,64^3) fp16 ch-first -> (128,128,128, VSTR=32-padded ch) fp16 channel-last.
// Pads (ch 28..31) written as 0 and never consumed; they make each voxel one aligned
// 64 B sector so the query kernel can gather with aligned dwordx4 loads.
__global__ void __launch_bounds__(256) idwt_last(const __half* __restrict__ vol1,
                                                 const float* __restrict__ details,
                                                 __half* __restrict__ out) {
    constexpr int D3 = 64 * 64 * 64;
    __shared__ unsigned short lds[4 * CCH * 130];  // 29,120 B
    int zc = blockIdx.x >> 6, yc = blockIdx.x & 63;
    int rowc = (zc * 64 + yc) * 64;
#pragma unroll 1
    for (int it = 0; it < 7; ++it) {           // 7*256 = 28ch * 64cells
        int item = it * 256 + threadIdx.x;
        int c = item >> 6, xc = item & 63;     // wave: fixed c, xc 0..63
        int base = c * D3 + rowc + xc;
        float cf[8];
        cf[0] = (float)vol1[base];
#pragma unroll
        for (int j = 0; j < 7; ++j) cf[j + 1] = details[j * (CCH * D3) + base];
        float o[8];
        haar8(cf, o);
#pragma unroll
        for (int k = 0; k < 8; ++k) {          // k = p*4+q*2+r
            int p2q = k >> 1, r = k & 1;
            lds[(p2q * CCH + c) * 130 + 2 * xc + r] = __half_as_ushort(__float2half(o[k]));
        }
    }
    __syncthreads();
    // 4 fine rows x (128 vox * 32 padded ch = 4096 halves = 512 uint4) = 2048 chunks.
#pragma unroll 1
    for (int it = 0; it < 8; ++it) {
        int t2 = it * 256 + threadIdx.x;       // 0..2047
        int plane = t2 >> 9;                   // fine row within 2x2
        int rem = t2 & 511;                    // uint4 index in row
        int p = plane >> 1, q = plane & 1;
        int vox = rem >> 2;                    // voxel 0..127
        int bc = (rem & 3) * 8;                // first channel of this uint4
        unsigned int h[8];
#pragma unroll
        for (int j = 0; j < 8; ++j) {
            int ch = bc + j;
            h[j] = (ch < CCH) ? (unsigned int)lds[(plane * CCH + ch) * 130 + vox] : 0u;
        }
        uint4 r4;
        r4.x = h[0] | (h[1] << 16);
        r4.y = h[2] | (h[3] << 16);
        r4.z = h[4] | (h[5] << 16);
        r4.w = h[6] | (h[7] << 16);
        long orow = ((long)(2 * zc + p) * 128 + (2 * yc + q)) * (128L * VSTR);
        ((uint4*)(out + orow))[rem] = r4;      // contiguous per wave
    }
}

// acc[0..27] += w * (14 half2 dwords from 4 aligned uint4; last 2 dwords of a3 are pad)
__device__ __forceinline__ void fma14(float acc[CCH], uint4 a0, uint4 a1, uint4 a2, uint4 a3,
                                      float w) {
    unsigned int u[14] = {a0.x, a0.y, a0.z, a0.w, a1.x, a1.y, a1.z, a1.w,
                          a2.x, a2.y, a2.z, a2.w, a3.x, a3.y};
#pragma unroll
    for (int d = 0; d < 14; ++d) {
        float2 f = __half22float2(*(__half2*)&u[d]);
        acc[2 * d]     += w * f.x;
        acc[2 * d + 1] += w * f.y;
    }
}

// One (y,z) row: x-pair of padded voxels = 128 B, 8 aligned 16B loads.
__device__ __forceinline__ void row2vox(float acc[CCH], const __half* __restrict__ vol,
                                        int gz, int gy, int xb, float a, float b) {
    const uint4* p = (const uint4*)(vol + (((long)(gz * 128 + gy) * 128 + xb) << 5));
    uint4 q0 = p[0], q1 = p[1], q2 = p[2], q3 = p[3];
    uint4 q4 = p[4], q5 = p[5], q6 = p[6], q7 = p[7];
    fma14(acc, q0, q1, q2, q3, a);   // voxel xb
    fma14(acc, q4, q5, q6, q7, b);   // voxel xb+1
}

// Direct gather in original query order: coalesced xyz read, coalesced out write,
// 8-corner gather served by L3 (vol2 = 134 MB, Infinity-Cache-resident after idwt_last).
__global__ void __launch_bounds__(256) query_direct(const float* __restrict__ xyz,
                                                    const __half* __restrict__ vol,
                                                    float* __restrict__ out, int N) {
    int i = blockIdx.x * 256 + threadIdx.x;
    if (i >= N) return;
    float x = xyz[3 * i], y = xyz[3 * i + 1], z = xyz[3 * i + 2];
    const float R1 = 63.5f, IB = 1.0f / 1.5f;
    float px = (x * IB + 1.0f) * R1;
    float py = (y * IB + 1.0f) * R1;
    float pz = (z * IB + 1.0f) * R1;
    float flx = floorf(px), fly = floorf(py), flz = floorf(pz);
    int ix0 = (int)flx, iy0 = (int)fly, iz0 = (int)flz;
    float fx = px - flx, fy = py - fly, fz = pz - flz;
    // xyz in [-1.5, 1.5) => p* in [~-2e-6, 127) => i*0 in [-1, 126]. Clamps defensive.
    int xb = min(max(ix0, 0), 126);            // pair [xb, xb+1] always in-bounds
    bool xn = ix0 < 0;                         // FP edge: px ~ -2e-6
    float u0 = xn ? fx : 1.0f - fx;            // weight for voxel xb
    float u1 = xn ? 0.0f : fx;                 // weight for voxel xb+1
    float wy0 = (iy0 >= 0) ? 1.0f - fy : 0.0f, wy1 = fy;
    float wz0 = (iz0 >= 0) ? 1.0f - fz : 0.0f, wz1 = fz;
    int gy0 = max(iy0, 0), gy1 = min(iy0 + 1, 127);
    int gz0 = max(iz0, 0), gz1 = min(iz0 + 1, 127);

    float acc[CCH];
#pragma unroll
    for (int k = 0; k < CCH; ++k) acc[k] = 0.0f;
    float wA = wz0 * wy0, wB = wz0 * wy1, wC = wz1 * wy0, wD = wz1 * wy1;
    row2vox(acc, vol, gz0, gy0, xb, wA * u0, wA * u1);
    row2vox(acc, vol, gz0, gy1, xb, wB * u0, wB * u1);
    row2vox(acc, vol, gz1, gy0, xb, wC * u0, wC * u1);
    row2vox(acc, vol, gz1, gy1, xb, wD * u0, wD * u1);

    f32x4* o4 = (f32x4*)(out + (long)i * CCH);  // 112 B/row, contiguous in i
#pragma unroll
    for (int j = 0; j < 7; ++j) {
        f32x4 v = {acc[4 * j], acc[4 * j + 1], acc[4 * j + 2], acc[4 * j + 3]};
        __builtin_nontemporal_store(v, o4 + j);  // streamed: don't pollute L2
    }
}

extern "C" void kernel_launch(void* const* d_in, const int* in_sizes, int n_in,
                              void* d_out, int out_size, void* d_ws, size_t ws_size,
                              hipStream_t stream) {
    const float* approx = (const float*)d_in[0];   // (28,16,16,16)
    const float* det0   = (const float*)d_in[1];   // (7,28,16,16,16)
    const float* det1   = (const float*)d_in[2];   // (7,28,32,32,32)
    const float* det2   = (const float*)d_in[3];   // (7,28,64,64,64)
    const float* xyz    = (const float*)d_in[4];   // (N,3)
    int N = in_sizes[4] / 3;

    char* ws = (char*)d_ws;
    // vol1 @0          : 14,680,064  (28*64^3 fp16, ch-first)
    // vol0 @14,680,064 : 1,835,008   (28*32^3 fp16) -- dead after idwt_cf_h<5>
    // vol2 @14,680,064 : 134,217,728 (128^3 * 32-padded ch fp16, channel-last)
    //                    aliases vol0 (written only by idwt_last, after vol0 is dead)
    // total 148,897,792 B (< previously-proven 150,004,752 B)
    __half* vol1 = (__half*)ws;
    __half* vol0 = (__half*)(ws + 14680064);
    __half* vol2 = (__half*)(ws + 14680064);

    idwt_cf_h<4, float><<<448, 256, 0, stream>>>(approx, det0, vol0);
    idwt_cf_h<5, __half><<<3584, 256, 0, stream>>>(vol0, det1, vol1);
    idwt_last<<<4096, 256, 0, stream>>>(vol1, det2, vol2);
    int nb = (N + 255) / 256;
    query_direct<<<nb, 256, 0, stream>>>(xyz, vol2, (float*)d_out, N);
}

// Round 3
// 750.375 us; speedup vs baseline: 1.1472x; 1.1472x over previous
//
#include <hip/hip_runtime.h>
#include <hip/hip_fp16.h>

#define INVS 0.35355339059327373f  // 1/(2*sqrt(2))
#define CCH 28
#define QRS 127                    // query LDS row stride (dwords): odd -> bank spread

typedef float f32x4 __attribute__((ext_vector_type(4)));

// 8-coeff 3D Haar butterfly. c[b], b = u*4+v*2+w; o[p*4+q*2+r].
__device__ __forceinline__ void haar8(const float c[8], float o[8]) {
    float t00p = c[0] + c[1], t00m = c[0] - c[1];
    float t01p = c[2] + c[3], t01m = c[2] - c[3];
    float t10p = c[4] + c[5], t10m = c[4] - c[5];
    float t11p = c[6] + c[7], t11m = c[6] - c[7];
    float u00p = t00p + t01p, u00m = t00m + t01m;
    float u01p = t00p - t01p, u01m = t00m - t01m;
    float u10p = t10p + t11p, u10m = t10m + t11m;
    float u11p = t10p - t11p, u11m = t10m - t11m;
    o[0] = (u00p + u10p) * INVS;  o[1] = (u00m + u10m) * INVS;
    o[2] = (u01p + u11p) * INVS;  o[3] = (u01m + u11m) * INVS;
    o[4] = (u00p - u10p) * INVS;  o[5] = (u00m - u10m) * INVS;
    o[6] = (u01p - u11p) * INVS;  o[7] = (u01m - u11m) * INVS;
}

// Pixel coords with NO fma contraction (__f*_rn): bit-identical across kernels,
// so hist_k and scatter_k agree on every query's cell.
__device__ __forceinline__ float3 pixcoord(float x, float y, float z) {
    const float R1 = 63.5f, IB = 1.0f / 1.5f;
    float3 p;
    p.x = __fmul_rn(__fadd_rn(__fmul_rn(x, IB), 1.0f), R1);
    p.y = __fmul_rn(__fadd_rn(__fmul_rn(y, IB), 1.0f), R1);
    p.z = __fmul_rn(__fadd_rn(__fmul_rn(z, IB), 1.0f), R1);
    return p;
}
// Cells: 8x8 in x/y, 4 in z -> 16*16*32 = 8192 cells.
__device__ __forceinline__ int cell_of(float3 p) {
    int cx = min(max((int)floorf(p.x), 0), 127) >> 3;
    int cy = min(max((int)floorf(p.y), 0), 127) >> 3;
    int cz = min(max((int)floorf(p.z), 0), 127) >> 2;
    return (cz * 16 + cy) * 16 + cx;
}

// Level 0: channel-first fp16 output (C, 2D, 2D, 2D). x-fastest threads.
template <int LOGD, typename TA>
__global__ void idwt_cf_h(const TA* __restrict__ approx,
                          const float* __restrict__ details,
                          __half* __restrict__ out) {
    constexpr int D  = 1 << LOGD;
    constexpr int D3 = D * D * D;
    int t  = blockIdx.x * blockDim.x + threadIdx.x;
    int xc = t & (D - 1);
    int yc = (t >> LOGD) & (D - 1);
    int zc = (t >> (2 * LOGD)) & (D - 1);
    int c  = t >> (3 * LOGD);
    if (c >= CCH) return;
    int base = c * D3 + ((zc * D + yc) * D + xc);
    float cf[8];
    cf[0] = (float)approx[base];
#pragma unroll
    for (int j = 0; j < 7; ++j) cf[j + 1] = details[j * (CCH * D3) + base];
    float o[8];
    haar8(cf, o);
    constexpr int D2 = 2 * D;
    __half2* outv = (__half2*)out;  // half2 = x-pair
    int ob = (((c * D2 + 2 * zc) * D2 + 2 * yc) * D + xc);
    __half2 h01, h23, h45, h67;
    h01.x = __float2half(o[0]); h01.y = __float2half(o[1]);
    h23.x = __float2half(o[2]); h23.y = __float2half(o[3]);
    h45.x = __float2half(o[4]); h45.y = __float2half(o[5]);
    h67.x = __float2half(o[6]); h67.y = __float2half(o[7]);
    outv[ob]              = h01;
    outv[ob + D]          = h23;
    outv[ob + D2 * D]     = h45;
    outv[ob + D2 * D + D] = h67;
}

// Level 1, x-paired: (28,32^3) + det1 -> (28,64^3) ch-first fp16.
// float2/half2 loads, uint2 stores: half the instruction count of the scalar version.
__global__ void idwt_cf2(const __half* __restrict__ approx,
                         const float* __restrict__ details,
                         __half* __restrict__ out) {
    constexpr int D = 32, D3 = D * D * D;
    int t  = blockIdx.x * 256 + threadIdx.x;
    int xp = t & 15;               // x-pair 0..15
    int yc = (t >> 4) & 31;
    int zc = (t >> 9) & 31;
    int c  = t >> 14;              // grid exact: 28*16384/256 = 1792 blocks
    if (c >= CCH) return;
    int base = c * D3 + ((zc * D + yc) * D + 2 * xp);
    __half2 a2 = *(const __half2*)(approx + base);
    float cfA[8], cfB[8];
    cfA[0] = __half2float(a2.x);
    cfB[0] = __half2float(a2.y);
#pragma unroll
    for (int j = 0; j < 7; ++j) {
        float2 d2 = *(const float2*)(details + j * (CCH * D3) + base);
        cfA[j + 1] = d2.x;
        cfB[j + 1] = d2.y;
    }
    float oA[8], oB[8];
    haar8(cfA, oA);
    haar8(cfB, oB);
    // Fine voxels: A -> x = 4xp+{0,1}, B -> x = 4xp+{2,3}: one uint2 per fine row.
    uint2* outv = (uint2*)out;     // uint2 = 4 halfs
#pragma unroll
    for (int p = 0; p < 2; ++p)
#pragma unroll
        for (int q = 0; q < 2; ++q) {
            int k0 = p * 4 + q * 2;
            __half2 lo, hi;
            lo.x = __float2half(oA[k0]);     lo.y = __float2half(oA[k0 + 1]);
            hi.x = __float2half(oB[k0]);     hi.y = __float2half(oB[k0 + 1]);
            uint2 v;
            v.x = *(unsigned int*)&lo;
            v.y = *(unsigned int*)&hi;
            long oi = (((long)(c * 64 + 2 * zc + p) * 64 + 2 * yc + q) * 64 + 4 * xp) >> 2;
            outv[oi] = v;
        }
}

// Level 2: (28,64^3) fp16 ch-first -> (128,128,128,28) fp16 channel-last (dense).
// Phase 1: channel-strided full unroll -> 56 independent global loads in flight,
// packed ds_write_b32 (4 LDS writes/voxel instead of 8 b16).
__global__ void __launch_bounds__(256) idwt_last(const __half* __restrict__ vol1,
                                                 const float* __restrict__ details,
                                                 __half* __restrict__ out) {
    constexpr int D3 = 64 * 64 * 64;
    __shared__ unsigned int lds4[4 * CCH * 65];          // 29,120 B
    unsigned short* lds = (unsigned short*)lds4;         // [plane*28+ch]*130 + vox
    int zc = blockIdx.x >> 6, yc = blockIdx.x & 63;
    int rowc = (zc * 64 + yc) * 64;
    int xc = threadIdx.x & 63, cg = threadIdx.x >> 6;    // cg 0..3
#pragma unroll
    for (int k = 0; k < 7; ++k) {
        int c = cg + 4 * k;                              // covers 0..27 exactly
        int base = c * D3 + rowc + xc;
        float cf[8];
        cf[0] = (float)vol1[base];
#pragma unroll
        for (int j = 0; j < 7; ++j) cf[j + 1] = details[j * (CCH * D3) + base];
        float o[8];
        haar8(cf, o);
#pragma unroll
        for (int m = 0; m < 4; ++m) {                    // m = p*2+q
            __half2 h;
            h.x = __float2half(o[2 * m]);
            h.y = __float2half(o[2 * m + 1]);
            lds4[(m * CCH + c) * 65 + xc] = *(unsigned int*)&h;
        }
    }
    __syncthreads();
    // 4 fine rows x (128 vox * 28 ch = 3584 halves = 448 uint4) = 1792 chunks.
#pragma unroll
    for (int it = 0; it < 7; ++it) {
        int t2 = it * 256 + threadIdx.x;       // 0..1791
        int plane = t2 / 448;
        int rem = t2 - plane * 448;
        int p = plane >> 1, q = plane & 1;
        unsigned int h[8];
#pragma unroll
        for (int j = 0; j < 8; ++j) {
            int f = rem * 8 + j;
            int vox = f / 28;
            int ch = f - 28 * vox;
            h[j] = lds[(plane * CCH + ch) * 130 + vox];
        }
        uint4 r4;
        r4.x = h[0] | (h[1] << 16);
        r4.y = h[2] | (h[3] << 16);
        r4.z = h[4] | (h[5] << 16);
        r4.w = h[6] | (h[7] << 16);
        long orow = ((long)(2 * zc + p) * 128 + (2 * yc + q)) * (128 * CCH);
        ((uint4*)(out + orow))[rem] = r4;      // contiguous per wave
    }
}

__global__ void hist_k(const float* __restrict__ xyz, int* __restrict__ hist, int N) {
    int i = blockIdx.x * 256 + threadIdx.x;
    if (i >= N) return;
    float3 p = pixcoord(xyz[3 * i], xyz[3 * i + 1], xyz[3 * i + 2]);
    atomicAdd(&hist[cell_of(p)], 1);
}

// 8192 cells: 256 threads x 32 cells each.
__global__ void __launch_bounds__(256) scan_k(const int* __restrict__ hist,
                                              int* __restrict__ off,
                                              int* __restrict__ cursor) {
    __shared__ int part[256];
    int t = threadIdx.x;
    int loc[32], s = 0;
#pragma unroll
    for (int i = 0; i < 32; ++i) { loc[i] = s; s += hist[t * 32 + i]; }
    part[t] = s;
    __syncthreads();
    for (int d = 1; d < 256; d <<= 1) {        // Hillis-Steele inclusive
        int v = (t >= d) ? part[t - d] : 0;
        __syncthreads();
        part[t] += v;
        __syncthreads();
    }
    int excl = part[t] - s;
#pragma unroll
    for (int i = 0; i < 32; ++i) {
        int o = excl + loc[i];
        off[t * 32 + i] = o;
        cursor[t * 32 + i] = o;
    }
    if (t == 255) off[8192] = part[255];
}

__global__ void scatter_k(const float* __restrict__ xyz, int* __restrict__ cursor,
                          float4* __restrict__ recs, int N) {
    int i = blockIdx.x * 256 + threadIdx.x;
    if (i >= N) return;
    float3 p = pixcoord(xyz[3 * i], xyz[3 * i + 1], xyz[3 * i + 2]);
    int cell = cell_of(p);
    int pos = atomicAdd(&cursor[cell], 1);
    recs[pos] = make_float4(__int_as_float(i), p.x, p.y, p.z);
}

// One block per 8x8x4 cell: stage 9x9x5 halo region in LDS, serve queries from LDS.
__global__ void __launch_bounds__(256, 7) query_cell(const float4* __restrict__ recs,
                                                     const int* __restrict__ off,
                                                     const __half* __restrict__ vol,
                                                     float* __restrict__ out) {
    __shared__ unsigned int lds[45 * QRS];     // 22,860 B
    int cell = blockIdx.x;
    int cx = cell & 15, cy = (cell >> 4) & 15, cz = cell >> 8;  // cz 0..31
    const unsigned int* vd = (const unsigned int*)vol;
    const long VOLDW = 128L * 128 * 128 * 14;  // volume in dwords
    // Region: 45 rows (lz,ly) x 9 voxels x 14 dwords = 126 dwords = 63 uint2 each.
    for (int e = threadIdx.x; e < 45 * 63; e += 256) {
        int row = e / 63;
        int k2  = e - row * 63;
        int lz = row / 9, ly = row - 9 * lz;
        int gz = min(4 * cz + lz, 127), gy = min(8 * cy + ly, 127);
        long g = ((long)(gz * 128 + gy) * 128 + 8 * cx) * 14 + 2 * k2;
        g = min(g, VOLDW - 2);                 // x-overrun at cx=15: finite junk, w=0
        uint2 v = *(const uint2*)(vd + g);     // g even -> 8B aligned
        lds[row * QRS + 2 * k2]     = v.x;
        lds[row * QRS + 2 * k2 + 1] = v.y;
    }
    __syncthreads();
    int i1 = off[cell + 1];
    for (int i = off[cell] + (int)threadIdx.x; i < i1; i += 256) {
        float4 r = recs[i];
        int q = __float_as_int(r.x);
        float px = r.y, py = r.z, pz = r.w;
        float flx = floorf(px), fly = floorf(py), flz = floorf(pz);
        int ix0 = (int)flx, iy0 = (int)fly, iz0 = (int)flz;
        float fx = px - flx, fy = py - fly, fz = pz - flz;
        float acc[CCH];
#pragma unroll
        for (int k = 0; k < CCH; ++k) acc[k] = 0.0f;
#pragma unroll
        for (int dz = 0; dz < 2; ++dz) {
            int iz = iz0 + dz;
            bool vz = (iz >= 0) & (iz < 128);
            float wz = dz ? fz : 1.0f - fz;
            int lzc = min(max(iz, 0), 127) - 4 * cz;
#pragma unroll
            for (int dy = 0; dy < 2; ++dy) {
                int iy = iy0 + dy;
                bool vy = (iy >= 0) & (iy < 128);
                float wy = dy ? fy : 1.0f - fy;
                int lyc = min(max(iy, 0), 127) - 8 * cy;
#pragma unroll
                for (int dx = 0; dx < 2; ++dx) {
                    int ix = ix0 + dx;
                    bool vx = (ix >= 0) & (ix < 128);
                    float wx = dx ? fx : 1.0f - fx;
                    int lxc = min(max(ix, 0), 127) - 8 * cx;
                    float w = (vx & vy & vz) ? (wx * wy * wz) : 0.0f;
                    const unsigned int* pr = &lds[(lzc * 9 + lyc) * QRS + 14 * lxc];
#pragma unroll
                    for (int j = 0; j < 7; ++j) {
                        unsigned int u0 = pr[2 * j], u1 = pr[2 * j + 1];
                        float2 f0 = __half22float2(*(__half2*)&u0);
                        float2 f1 = __half22float2(*(__half2*)&u1);
                        acc[4 * j + 0] += w * f0.x;
                        acc[4 * j + 1] += w * f0.y;
                        acc[4 * j + 2] += w * f1.x;
                        acc[4 * j + 3] += w * f1.y;
                    }
                }
            }
        }
        // Nontemporal: scattered 112B rows — skip L2 write-allocate line fills.
        f32x4* o4 = (f32x4*)(out + (long)q * CCH);  // 112B rows, 16B aligned
#pragma unroll
        for (int j = 0; j < 7; ++j) {
            f32x4 v = {acc[4 * j], acc[4 * j + 1], acc[4 * j + 2], acc[4 * j + 3]};
            __builtin_nontemporal_store(v, o4 + j);
        }
    }
}

extern "C" void kernel_launch(void* const* d_in, const int* in_sizes, int n_in,
                              void* d_out, int out_size, void* d_ws, size_t ws_size,
                              hipStream_t stream) {
    const float* approx = (const float*)d_in[0];   // (28,16,16,16)
    const float* det0   = (const float*)d_in[1];   // (7,28,16,16,16)
    const float* det1   = (const float*)d_in[2];   // (7,28,32,32,32)
    const float* det2   = (const float*)d_in[3];   // (7,28,64,64,64)
    const float* xyz    = (const float*)d_in[4];   // (N,3)
    int N = in_sizes[4] / 3;

    char* ws = (char*)d_ws;
    // vol0  @0          : 1,835,008   (28*32^3 fp16)
    // vol1  @1,835,008  : 14,680,064  (28*64^3 fp16)
    // vol2  @16,515,072 : 117,440,512 (128^3*28 fp16, channel-last)
    // hist  @133,955,584: 32,768      (8192 cells)
    // off   @133,988,352: 32,772 (pad to 32,784)
    // curs  @134,021,136: 32,768
    // recs  @134,053,904: N*16 -> total 150,053,904 B (proven in round 1)
    __half* vol0 = (__half*)ws;
    __half* vol1 = (__half*)(ws + 1835008);
    __half* vol2 = (__half*)(ws + 16515072);
    int*    hist = (int*)(ws + 133955584);
    int*    off  = (int*)(ws + 133988352);
    int*    curs = (int*)(ws + 134021136);
    float4* recs = (float4*)(ws + 134053904);

    hipMemsetAsync(hist, 0, 8192 * sizeof(int), stream);
    idwt_cf_h<4, float><<<448, 256, 0, stream>>>(approx, det0, vol0);
    idwt_cf2<<<1792, 256, 0, stream>>>(vol0, det1, vol1);
    idwt_last<<<4096, 256, 0, stream>>>(vol1, det2, vol2);
    int nb = (N + 255) / 256;
    hist_k<<<nb, 256, 0, stream>>>(xyz, hist, N);
    scan_k<<<1, 256, 0, stream>>>(hist, off, curs);
    scatter_k<<<nb, 256, 0, stream>>>(xyz, curs, recs, N);
    query_cell<<<8192, 256, 0, stream>>>(recs, off, vol2, (float*)d_out);
}

// Round 4
// 517.445 us; speedup vs baseline: 1.6636x; 1.4502x over previous
//
#include <hip/hip_runtime.h>
#include <hip/hip_fp16.h>

#define INVS 0.35355339059327373f  // 1/(2*sqrt(2))
#define CCH 28
#define QRS 127                    // query LDS row stride (dwords): odd -> bank spread
#define CAP 256                    // bucket capacity (mean 122, sd 11 -> 12 sigma)

typedef float f32x4 __attribute__((ext_vector_type(4)));

// 8-coeff 3D Haar butterfly. c[b], b = u*4+v*2+w; o[p*4+q*2+r].
__device__ __forceinline__ void haar8(const float c[8], float o[8]) {
    float t00p = c[0] + c[1], t00m = c[0] - c[1];
    float t01p = c[2] + c[3], t01m = c[2] - c[3];
    float t10p = c[4] + c[5], t10m = c[4] - c[5];
    float t11p = c[6] + c[7], t11m = c[6] - c[7];
    float u00p = t00p + t01p, u00m = t00m + t01m;
    float u01p = t00p - t01p, u01m = t00m - t01m;
    float u10p = t10p + t11p, u10m = t10m + t11m;
    float u11p = t10p - t11p, u11m = t10m - t11m;
    o[0] = (u00p + u10p) * INVS;  o[1] = (u00m + u10m) * INVS;
    o[2] = (u01p + u11p) * INVS;  o[3] = (u01m + u11m) * INVS;
    o[4] = (u00p - u10p) * INVS;  o[5] = (u00m - u10m) * INVS;
    o[6] = (u01p - u11p) * INVS;  o[7] = (u01m - u11m) * INVS;
}

// Pixel coords with NO fma contraction (__f*_rn): bit-identical across kernels,
// so scatter_k and query_cell agree on every query's cell and weights.
__device__ __forceinline__ float3 pixcoord(float x, float y, float z) {
    const float R1 = 63.5f, IB = 1.0f / 1.5f;
    float3 p;
    p.x = __fmul_rn(__fadd_rn(__fmul_rn(x, IB), 1.0f), R1);
    p.y = __fmul_rn(__fadd_rn(__fmul_rn(y, IB), 1.0f), R1);
    p.z = __fmul_rn(__fadd_rn(__fmul_rn(z, IB), 1.0f), R1);
    return p;
}
// Cells: 8x8 in x/y, 4 in z -> 16*16*32 = 8192 cells.
__device__ __forceinline__ int cell_of(float3 p) {
    int cx = min(max((int)floorf(p.x), 0), 127) >> 3;
    int cy = min(max((int)floorf(p.y), 0), 127) >> 3;
    int cz = min(max((int)floorf(p.z), 0), 127) >> 2;
    return (cz * 16 + cy) * 16 + cx;
}

// Fused levels 0+1: approx(28,16^3)+det0 -> [regs] -> +det1 -> vol1(28,64^3) fp16.
// Haar is local: one thread owns one coarse voxel through both levels; vol0 never
// touches memory. 1792 blocks x 64.
__global__ void __launch_bounds__(64) idwt01(const float* __restrict__ approx,
                                             const float* __restrict__ det0,
                                             const float* __restrict__ det1,
                                             __half* __restrict__ vol1) {
    constexpr int D03 = 16 * 16 * 16, D13 = 32 * 32 * 32;
    int t = blockIdx.x * 64 + threadIdx.x;     // 28 * 4096 threads exactly
    int x0 = t & 15, y0 = (t >> 4) & 15, z0 = (t >> 8) & 15, c = t >> 12;
    int base0 = c * D03 + ((z0 * 16 + y0) * 16 + x0);
    float cf[8];
    cf[0] = approx[base0];
#pragma unroll
    for (int j = 0; j < 7; ++j) cf[j + 1] = det0[j * (CCH * D03) + base0];
    float v0[8];
    haar8(cf, v0);
    unsigned int hbuf[4][4][2];                // [pz][py][x-pair r] packed half2
#pragma unroll
    for (int p = 0; p < 2; ++p)
#pragma unroll
        for (int q = 0; q < 2; ++q)
#pragma unroll
            for (int r = 0; r < 2; ++r) {
                int z1 = 2 * z0 + p, y1 = 2 * y0 + q, x1 = 2 * x0 + r;
                int base1 = c * D13 + ((z1 * 32 + y1) * 32 + x1);
                float cg[8];
                cg[0] = v0[p * 4 + q * 2 + r];
#pragma unroll
                for (int j = 0; j < 7; ++j) cg[j + 1] = det1[j * (CCH * D13) + base1];
                float o[8];
                haar8(cg, o);
#pragma unroll
                for (int sz = 0; sz < 2; ++sz)
#pragma unroll
                    for (int sy = 0; sy < 2; ++sy) {
                        __half2 h;
                        h.x = __float2half(o[sz * 4 + sy * 2 + 0]);
                        h.y = __float2half(o[sz * 4 + sy * 2 + 1]);
                        hbuf[2 * p + sz][2 * q + sy][r] = *(unsigned int*)&h;
                    }
            }
#pragma unroll
    for (int pz = 0; pz < 4; ++pz)
#pragma unroll
        for (int py = 0; py < 4; ++py) {
            uint2 v;
            v.x = hbuf[pz][py][0];
            v.y = hbuf[pz][py][1];
            long oi = (((long)(c * 64 + 4 * z0 + pz) * 64 + (4 * y0 + py)) * 64 + 4 * x0) >> 2;
            ((uint2*)vol1)[oi] = v;
        }
}

// Level 2: (28,64^3) fp16 ch-first -> (128,128,128,28) fp16 channel-last (dense).
__global__ void __launch_bounds__(256) idwt_last(const __half* __restrict__ vol1,
                                                 const float* __restrict__ details,
                                                 __half* __restrict__ out) {
    constexpr int D3 = 64 * 64 * 64;
    __shared__ unsigned int lds4[4 * CCH * 65];          // 29,120 B
    unsigned short* lds = (unsigned short*)lds4;         // [plane*28+ch]*130 + vox
    int zc = blockIdx.x >> 6, yc = blockIdx.x & 63;
    int rowc = (zc * 64 + yc) * 64;
    int xc = threadIdx.x & 63, cg = threadIdx.x >> 6;    // cg 0..3
#pragma unroll
    for (int k = 0; k < 7; ++k) {
        int c = cg + 4 * k;                              // covers 0..27 exactly
        int base = c * D3 + rowc + xc;
        float cf[8];
        cf[0] = (float)vol1[base];
#pragma unroll
        for (int j = 0; j < 7; ++j) cf[j + 1] = details[j * (CCH * D3) + base];
        float o[8];
        haar8(cf, o);
#pragma unroll
        for (int m = 0; m < 4; ++m) {                    // m = p*2+q
            __half2 h;
            h.x = __float2half(o[2 * m]);
            h.y = __float2half(o[2 * m + 1]);
            lds4[(m * CCH + c) * 65 + xc] = *(unsigned int*)&h;
        }
    }
    __syncthreads();
    // 4 fine rows x (128 vox * 28 ch = 3584 halves = 448 uint4) = 1792 chunks.
#pragma unroll
    for (int it = 0; it < 7; ++it) {
        int t2 = it * 256 + threadIdx.x;       // 0..1791
        int plane = t2 / 448;
        int rem = t2 - plane * 448;
        int p = plane >> 1, q = plane & 1;
        unsigned int h[8];
#pragma unroll
        for (int j = 0; j < 8; ++j) {
            int f = rem * 8 + j;
            int vox = f / 28;
            int ch = f - 28 * vox;
            h[j] = lds[(plane * CCH + ch) * 130 + vox];
        }
        uint4 r4;
        r4.x = h[0] | (h[1] << 16);
        r4.y = h[2] | (h[3] << 16);
        r4.z = h[4] | (h[5] << 16);
        r4.w = h[6] | (h[7] << 16);
        long orow = ((long)(2 * zc + p) * 128 + (2 * yc + q)) * (128 * CCH);
        ((uint4*)(out + orow))[rem] = r4;      // contiguous per wave
    }
}

// Bucket scatter: one atomicAdd per query, implicit offsets (cell*CAP). Overflow
// (impossible for ~uniform input: 12 sigma) is handled exactly via direct gather.
__global__ void scatter_k(const float* __restrict__ xyz, int* __restrict__ cursor,
                          unsigned int* __restrict__ recs, const __half* __restrict__ vol,
                          float* __restrict__ out, int N) {
    int i = blockIdx.x * 256 + threadIdx.x;
    if (i >= N) return;
    float3 p = pixcoord(xyz[3 * i], xyz[3 * i + 1], xyz[3 * i + 2]);
    int cell = cell_of(p);
    int pos = atomicAdd(&cursor[cell], 1);
    if (pos < CAP) {
        recs[cell * CAP + pos] = (unsigned int)i;
        return;
    }
    // Slow path: direct global gather (vol is dense channel-last, 56 B/voxel).
    float flx = floorf(p.x), fly = floorf(p.y), flz = floorf(p.z);
    int ix0 = (int)flx, iy0 = (int)fly, iz0 = (int)flz;
    float fx = p.x - flx, fy = p.y - fly, fz = p.z - flz;
    float acc[CCH];
#pragma unroll
    for (int k = 0; k < CCH; ++k) acc[k] = 0.0f;
    for (int dz = 0; dz < 2; ++dz) {
        int iz = iz0 + dz;
        bool vz = (iz >= 0) & (iz < 128);
        float wz = dz ? fz : 1.0f - fz;
        int gz = min(max(iz, 0), 127);
        for (int dy = 0; dy < 2; ++dy) {
            int iy = iy0 + dy;
            bool vy = (iy >= 0) & (iy < 128);
            float wy = dy ? fy : 1.0f - fy;
            int gy = min(max(iy, 0), 127);
            for (int dx = 0; dx < 2; ++dx) {
                int ix = ix0 + dx;
                bool vx = (ix >= 0) & (ix < 128);
                float wx = dx ? fx : 1.0f - fx;
                int gx = min(max(ix, 0), 127);
                float w = (vx & vy & vz) ? (wx * wy * wz) : 0.0f;
                const uint2* pv = (const uint2*)(vol + ((long)(gz * 128 + gy) * 128 + gx) * CCH);
#pragma unroll
                for (int j = 0; j < 7; ++j) {
                    uint2 u = pv[j];
                    float2 f0 = __half22float2(*(__half2*)&u.x);
                    float2 f1 = __half22float2(*(__half2*)&u.y);
                    acc[4 * j + 0] += w * f0.x;
                    acc[4 * j + 1] += w * f0.y;
                    acc[4 * j + 2] += w * f1.x;
                    acc[4 * j + 3] += w * f1.y;
                }
            }
        }
    }
#pragma unroll
    for (int k = 0; k < CCH; ++k) out[(long)i * CCH + k] = acc[k];
}

// One block per 8x8x4 cell: stage 9x9x5 halo region in LDS, serve queries from LDS.
__global__ void __launch_bounds__(256, 7) query_cell(const unsigned int* __restrict__ recs,
                                                     const int* __restrict__ cursor,
                                                     const float* __restrict__ xyz,
                                                     const __half* __restrict__ vol,
                                                     float* __restrict__ out) {
    __shared__ unsigned int lds[45 * QRS];     // 22,860 B
    int cell = blockIdx.x;
    int cx = cell & 15, cy = (cell >> 4) & 15, cz = cell >> 8;  // cz 0..31
    const unsigned int* vd = (const unsigned int*)vol;
    const long VOLDW = 128L * 128 * 128 * 14;  // volume in dwords
    // Region: 45 rows (lz,ly) x 9 voxels x 14 dwords = 126 dwords = 63 uint2 each.
    for (int e = threadIdx.x; e < 45 * 63; e += 256) {
        int row = e / 63;
        int k2  = e - row * 63;
        int lz = row / 9, ly = row - 9 * lz;
        int gz = min(4 * cz + lz, 127), gy = min(8 * cy + ly, 127);
        long g = ((long)(gz * 128 + gy) * 128 + 8 * cx) * 14 + 2 * k2;
        g = min(g, VOLDW - 2);                 // x-overrun at cx=15: finite junk, w=0
        uint2 v = *(const uint2*)(vd + g);     // g even -> 8B aligned
        lds[row * QRS + 2 * k2]     = v.x;
        lds[row * QRS + 2 * k2 + 1] = v.y;
    }
    __syncthreads();
    int cnt = min(cursor[cell], CAP);
    for (int k = threadIdx.x; k < cnt; k += 256) {
        int q = (int)recs[cell * CAP + k];
        float xq = xyz[3 * q], yq = xyz[3 * q + 1], zq = xyz[3 * q + 2];
        float3 p = pixcoord(xq, yq, zq);       // bit-identical to scatter_k's p
        float px = p.x, py = p.y, pz = p.z;
        float flx = floorf(px), fly = floorf(py), flz = floorf(pz);
        int ix0 = (int)flx, iy0 = (int)fly, iz0 = (int)flz;
        float fx = px - flx, fy = py - fly, fz = pz - flz;
        float acc[CCH];
#pragma unroll
        for (int k2 = 0; k2 < CCH; ++k2) acc[k2] = 0.0f;
#pragma unroll
        for (int dz = 0; dz < 2; ++dz) {
            int iz = iz0 + dz;
            bool vz = (iz >= 0) & (iz < 128);
            float wz = dz ? fz : 1.0f - fz;
            int lzc = min(max(iz, 0), 127) - 4 * cz;
#pragma unroll
            for (int dy = 0; dy < 2; ++dy) {
                int iy = iy0 + dy;
                bool vy = (iy >= 0) & (iy < 128);
                float wy = dy ? fy : 1.0f - fy;
                int lyc = min(max(iy, 0), 127) - 8 * cy;
#pragma unroll
                for (int dx = 0; dx < 2; ++dx) {
                    int ix = ix0 + dx;
                    bool vx = (ix >= 0) & (ix < 128);
                    float wx = dx ? fx : 1.0f - fx;
                    int lxc = min(max(ix, 0), 127) - 8 * cx;
                    float w = (vx & vy & vz) ? (wx * wy * wz) : 0.0f;
                    const unsigned int* pr = &lds[(lzc * 9 + lyc) * QRS + 14 * lxc];
#pragma unroll
                    for (int j = 0; j < 7; ++j) {
                        unsigned int u0 = pr[2 * j], u1 = pr[2 * j + 1];
                        float2 f0 = __half22float2(*(__half2*)&u0);
                        float2 f1 = __half22float2(*(__half2*)&u1);
                        acc[4 * j + 0] += w * f0.x;
                        acc[4 * j + 1] += w * f0.y;
                        acc[4 * j + 2] += w * f1.x;
                        acc[4 * j + 3] += w * f1.y;
                    }
                }
            }
        }
        f32x4* o4 = (f32x4*)(out + (long)q * CCH);  // 112B rows, 16B aligned
#pragma unroll
        for (int j = 0; j < 7; ++j) {
            f32x4 v = {acc[4 * j], acc[4 * j + 1], acc[4 * j + 2], acc[4 * j + 3]};
            o4[j] = v;                         // plain stores: L2 write-combines rows
        }
    }
}

extern "C" void kernel_launch(void* const* d_in, const int* in_sizes, int n_in,
                              void* d_out, int out_size, void* d_ws, size_t ws_size,
                              hipStream_t stream) {
    const float* approx = (const float*)d_in[0];   // (28,16,16,16)
    const float* det0   = (const float*)d_in[1];   // (7,28,16,16,16)
    const float* det1   = (const float*)d_in[2];   // (7,28,32,32,32)
    const float* det2   = (const float*)d_in[3];   // (7,28,64,64,64)
    const float* xyz    = (const float*)d_in[4];   // (N,3)
    int N = in_sizes[4] / 3;

    char* ws = (char*)d_ws;
    // vol1  @0          : 14,680,064  (28*64^3 fp16, ch-first)
    // vol2  @14,680,064 : 117,440,512 (128^3*28 fp16, channel-last)
    // curs  @132,120,576: 32,768      (8192 cells)
    // recs  @132,153,344: 8192*256*4 = 8,388,608 -> total 140,541,952 B (< 150,004,752 proven)
    __half*       vol1 = (__half*)ws;
    __half*       vol2 = (__half*)(ws + 14680064);
    int*          curs = (int*)(ws + 132120576);
    unsigned int* recs = (unsigned int*)(ws + 132153344);

    hipMemsetAsync(curs, 0, 8192 * sizeof(int), stream);
    idwt01<<<1792, 64, 0, stream>>>(approx, det0, det1, vol1);
    idwt_last<<<4096, 256, 0, stream>>>(vol1, det2, vol2);
    int nb = (N + 255) / 256;
    scatter_k<<<nb, 256, 0, stream>>>(xyz, curs, recs, vol2, (float*)d_out, N);
    query_cell<<<8192, 256, 0, stream>>>(recs, curs, xyz, vol2, (float*)d_out);
}